// Round 23
// baseline (143.673 us; speedup 1.0000x reference)
//
#include <hip/hip_runtime.h>

#define NUM_FACES 400000
#define NVIEW 4
#define NCHAN 64
#define IMGS 512
#define XT32 (IMGS / 32)   // 16 x-tiles of 32 px (one 128 B f32 cache line)
#define VPW 2              // vertices per wave (R19 optimum; 3 regressed)

typedef float f32x4 __attribute__((ext_vector_type(4)));
typedef float f32x2 __attribute__((ext_vector_type(2)));

__device__ __forceinline__ unsigned short f2bf(float f) {
    unsigned int u = __float_as_uint(f);
    return (unsigned short)((u + 0x7FFFu + ((u >> 16) & 1u)) >> 16);  // RNE
}

__device__ __forceinline__ void project_view(
    const float* __restrict__ cam_rot, const float* __restrict__ cam_trans,
    const float* __restrict__ Kmat, int v, float px, float py, float pz,
    float& x, float& y)
{
    const float* R  = cam_rot   + v * 9;
    const float* t  = cam_trans + v * 3;
    const float* Km = Kmat      + v * 9;
    float cx = R[0] * px + R[1] * py + R[2] * pz + t[0];
    float cy = R[3] * px + R[4] * py + R[5] * pz + t[1];
    float cz = R[6] * px + R[7] * py + R[8] * pz + t[2];
    float qx = Km[0] * cx + Km[1] * cy + Km[2] * cz;
    float qy = Km[3] * cx + Km[4] * cy + Km[5] * cz;
    float qz = Km[6] * cx + Km[7] * cy + Km[8] * cz;
    x = qx / qz;
    y = qy / qz;
}

// ---------------------------------------------------------------------------
// K0: zero table+flags.
// ---------------------------------------------------------------------------
__global__ void zero_ws_kernel(uint4* __restrict__ p, int n16) {
    int i = blockIdx.x * blockDim.x + threadIdx.x;
    if (i < n16) p[i] = make_uint4(0u, 0u, 0u, 0u);
}

// ---------------------------------------------------------------------------
// K1: scatter pix_to_face (int4-vectorized) into the visibility byte table.
// ---------------------------------------------------------------------------
__global__ void scatter_vis_kernel(const int4* __restrict__ p2f4,
                                   unsigned char* __restrict__ table) {
    const int pix4 = (NVIEW * IMGS * IMGS) / 4;
    int i = blockIdx.x * blockDim.x + threadIdx.x;
    if (i >= pix4) return;
    int4 f4 = p2f4[i];
    int v = i / ((IMGS * IMGS) / 4);
    unsigned char* tv = table + (size_t)v * NUM_FACES;
    if (f4.x >= 0) tv[f4.x] = 1;
    if (f4.y >= 0) tv[f4.y] = 1;
    if (f4.z >= 0) tv[f4.z] = 1;
    if (f4.w >= 0) tv[f4.w] = 1;
}

// ---------------------------------------------------------------------------
// K2: per-vertex prep. Marks touched 32-px tiles using EXACTLY the sampler's
// load addresses (coverage by construction). Writes xyv[N][8] + vmask[N].
// UNCHANGED from R19 (proven at 141.6).
// ---------------------------------------------------------------------------
__global__ void vprep_kernel(const float* __restrict__ verts,
                             const int* __restrict__ faces,
                             const float* __restrict__ cam_rot,
                             const float* __restrict__ cam_trans,
                             const float* __restrict__ Kmat,
                             const unsigned char* __restrict__ table, // [V,NUM_FACES]
                             float* __restrict__ xyv,                 // [N,8]
                             unsigned char* __restrict__ vmask,       // [N]
                             unsigned char* __restrict__ flags,       // [V,S,XT32]
                             int n_verts) {
    int n = blockIdx.x * blockDim.x + threadIdx.x;
    if (n >= n_verts) return;
    float px = verts[n * 3 + 0], py = verts[n * 3 + 1], pz = verts[n * 3 + 2];
    int f = faces[n];
    unsigned int m = 0;
    float xy[8];
#pragma unroll
    for (int v = 0; v < NVIEW; ++v) {
        float x, y;
        project_view(cam_rot, cam_trans, Kmat, v, px, py, pz, x, y);
        xy[v * 2 + 0] = x;
        xy[v * 2 + 1] = y;
        if (f >= 0 && table[(size_t)v * NUM_FACES + f]) m |= (1u << v);
        int ix0 = (int)floorf(x), iy0 = (int)floorf(y);
        int bx  = min(max(ix0, 0), IMGS - 2);        // sampler cols bx, bx+1
        int ry0 = min(max(iy0, 0), IMGS - 1);        // sampler rows
        int ry1 = min(max(iy0 + 1, 0), IMGS - 1);
        int ta = bx >> 5, tb = (bx + 1) >> 5;
        unsigned char* fv = flags + (size_t)v * IMGS * XT32;
        fv[ry0 * XT32 + ta] = 1;
        if (tb != ta) fv[ry0 * XT32 + tb] = 1;
        fv[ry1 * XT32 + ta] = 1;
        if (tb != ta) fv[ry1 * XT32 + tb] = 1;
    }
    if (m == 0) m = 15u;
    vmask[n] = (unsigned char)m;
    f32x4 a, b;
    a.x = xy[0]; a.y = xy[1]; a.z = xy[2]; a.w = xy[3];
    b.x = xy[4]; b.y = xy[5]; b.z = xy[6]; b.w = xy[7];
    f32x4* xp = reinterpret_cast<f32x4*>(xyv + (size_t)n * 8);
    xp[0] = a;
    xp[1] = b;
}

// ---------------------------------------------------------------------------
// K3: ROW transpose. One block per (v,y) row (2048 blocks instead of 32768):
// reads the row's 16 tile-flags once, walks marked tiles with a register-
// staged pipeline — the NEXT tile's two f32x4 loads are issued during the
// CURRENT tile's LDS-read/convert/store phase, keeping global reads in
// flight across the sync. Per-tile lane mappings byte-identical to R15.
// ---------------------------------------------------------------------------
__global__ __launch_bounds__(256) void transpose_feat_kernel(
    const float* __restrict__ feature,
    unsigned short* __restrict__ feat_t,
    const unsigned char* __restrict__ flags)
{
    int b = blockIdx.x;
    int y = b % IMGS;
    int v = b / IMGS;

    // 16 flags for this row, as a bitmask (block-uniform).
    uint4 fw = *reinterpret_cast<const uint4*>(
        flags + ((size_t)v * IMGS + y) * XT32);
    unsigned int fm = 0;
#pragma unroll
    for (int t = 0; t < 16; ++t) {
        unsigned int word = (t < 4) ? fw.x : (t < 8) ? fw.y : (t < 12) ? fw.z : fw.w;
        if ((word >> ((t & 3) * 8)) & 0xFFu) fm |= (1u << t);
    }
    if (fm == 0) return;

    __shared__ float tile[64 * 33];
    const size_t SS = (size_t)IMGS * IMGS;
    int tid = threadIdx.x;
    const float* srcrow = feature + (size_t)v * NCHAN * SS + (size_t)y * IMGS;
    unsigned short* dstrow = feat_t + ((size_t)v * IMGS + y) * IMGS * NCHAN;

    // load mapping (per tile): thread covers channels c0 and c0+32 at xq
    int lc0 = tid >> 3;            // 0..31
    int lxq = (tid & 7) * 4;       // 0..28

    int cur = __ffs(fm) - 1;
    f32x4 a = __builtin_nontemporal_load(
        reinterpret_cast<const f32x4*>(srcrow + (size_t)lc0 * SS + cur * 32 + lxq));
    f32x4 c = __builtin_nontemporal_load(
        reinterpret_cast<const f32x4*>(srcrow + (size_t)(lc0 + 32) * SS + cur * 32 + lxq));

    while (true) {
        unsigned int above = (cur < 31) ? (fm & ~((2u << cur) - 1u)) : 0u;
        int nxt = above ? (__ffs(above) - 1) : -1;

        // regs -> LDS
        {
            float* t0 = &tile[lc0 * 33 + lxq];
            t0[0] = a.x; t0[1] = a.y; t0[2] = a.z; t0[3] = a.w;
            float* t1 = &tile[(lc0 + 32) * 33 + lxq];
            t1[0] = c.x; t1[1] = c.y; t1[2] = c.z; t1[3] = c.w;
        }
        __syncthreads();

        // issue next tile's loads while this tile converts/stores
        f32x4 na, nc;
        if (nxt >= 0) {
            na = __builtin_nontemporal_load(
                reinterpret_cast<const f32x4*>(srcrow + (size_t)lc0 * SS + nxt * 32 + lxq));
            nc = __builtin_nontemporal_load(
                reinterpret_cast<const f32x4*>(srcrow + (size_t)(lc0 + 32) * SS + nxt * 32 + lxq));
        }

        // LDS -> convert -> global (mapping identical to R15)
        unsigned short* dst = dstrow + (size_t)(cur * 32) * NCHAN;
#pragma unroll
        for (int i = 0; i < 2; ++i) {
            int lin = i * 256 + tid;
            int x  = lin >> 4;              // pixel 0..31
            int c0 = (lin & 15) * 4;        // channel quad
            ushort4 w;
            w.x = f2bf(tile[(c0 + 0) * 33 + x]);
            w.y = f2bf(tile[(c0 + 1) * 33 + x]);
            w.z = f2bf(tile[(c0 + 2) * 33 + x]);
            w.w = f2bf(tile[(c0 + 3) * 33 + x]);
            *reinterpret_cast<ushort4*>(dst + (size_t)x * NCHAN + c0) = w;
        }
        if (nxt < 0) break;
        __syncthreads();   // LDS consumed; safe to overwrite next iteration
        a = na; c = nc; cur = nxt;
    }
}

// ---------------------------------------------------------------------------
// K4: sampler, VPW=2 (exact R19 kernel — proven 141.6 optimum).
// ---------------------------------------------------------------------------
__global__ __launch_bounds__(256) void project_sample_bf16_kernel(
    const float* __restrict__ xyv,               // [N,8]
    const unsigned char* __restrict__ vmask,     // [N]
    const unsigned short* __restrict__ feat_t,   // [V,S,S,C] bf16
    float* __restrict__ out,                     // [N,C]
    int n_verts)
{
    int n0 = blockIdx.x * (4 * VPW) + (threadIdx.x >> 6) * VPW;
    int lane  = threadIdx.x & 63;
    int lhalf = lane >> 5;
    int cp    = lane & 31;

    unsigned int m[VPW];
    f32x4 xya[VPW], xyb[VPW];
#pragma unroll
    for (int s = 0; s < VPW; ++s) {
        int n = n0 + s;
        if (n < n_verts) {
            m[s] = vmask[n];
            const f32x4* xp = reinterpret_cast<const f32x4*>(xyv + (size_t)n * 8);
            xya[s] = xp[0];
            xyb[s] = xp[1];
        } else {
            m[s] = 0u;
            xya[s] = 0.f;
            xyb[s] = 0.f;
        }
    }

    unsigned int u0[VPW][NVIEW], u1[VPW][NVIEW];
    float w0[VPW][NVIEW], w1[VPW][NVIEW];
#pragma unroll
    for (int s = 0; s < VPW; ++s) {
        float xs[NVIEW] = {xya[s].x, xya[s].z, xyb[s].x, xyb[s].z};
        float ys[NVIEW] = {xya[s].y, xya[s].w, xyb[s].y, xyb[s].w};
#pragma unroll
        for (int v = 0; v < NVIEW; ++v) {
            u0[s][v] = 0u; u1[s][v] = 0u; w0[s][v] = 0.f; w1[s][v] = 0.f;
            if (m[s] & (1u << v)) {   // wave-uniform
                float x = xs[v], y = ys[v];
                float x0f = floorf(x), y0f = floorf(y);
                float wx1 = x - x0f, wx0 = 1.f - wx1;
                float wy1 = y - y0f, wy0 = 1.f - wy1;
                int ix0 = (int)x0f, iy0 = (int)y0f;
                int ix1 = ix0 + 1, iy1 = iy0 + 1;

                int bx = min(max(ix0, 0), IMGS - 2);
                int k  = bx + lhalf;
                float wxk = (k == ix0 ? wx0 : 0.f) + (k == ix1 ? wx1 : 0.f);

                int ry0 = min(max(iy0, 0), IMGS - 1);
                int ry1 = min(max(iy1, 0), IMGS - 1);
                float wyr0 = (iy0 >= 0 && iy0 <= IMGS - 1) ? wy0 : 0.f;
                float wyr1 = (iy1 >= 0 && iy1 <= IMGS - 1) ? wy1 : 0.f;

                const unsigned int* fv32 = reinterpret_cast<const unsigned int*>(
                    feat_t + (size_t)v * IMGS * IMGS * NCHAN);
                u0[s][v] = fv32[((size_t)ry0 * IMGS + bx) * 32 + lane];
                u1[s][v] = fv32[((size_t)ry1 * IMGS + bx) * 32 + lane];
                w0[s][v] = wxk * wyr0;
                w1[s][v] = wxk * wyr1;
            }
        }
    }

#pragma unroll
    for (int s = 0; s < VPW; ++s) {
        if (m[s] == 0u) continue;   // wave-uniform (only the tail block)
        float accx = 0.f, accy = 0.f;
#pragma unroll
        for (int v = 0; v < NVIEW; ++v) {
            accx += __uint_as_float(u0[s][v] << 16) * w0[s][v]
                  + __uint_as_float(u1[s][v] << 16) * w1[s][v];
            accy += __uint_as_float(u0[s][v] & 0xFFFF0000u) * w0[s][v]
                  + __uint_as_float(u1[s][v] & 0xFFFF0000u) * w1[s][v];
        }
        accx += __shfl_xor(accx, 32, 64);
        accy += __shfl_xor(accy, 32, 64);
        if (lhalf == 0) {
            float r = 1.f / (float)__popc(m[s]);
            f32x2 o; o.x = accx * r; o.y = accy * r;
            __builtin_nontemporal_store(o,
                reinterpret_cast<f32x2*>(out + (size_t)(n0 + s) * NCHAN) + cp);
        }
    }
}

// ---------------------------------------------------------------------------
// Fallback (small ws): direct f32 gather from [V,C,S,S].
// ---------------------------------------------------------------------------
__global__ __launch_bounds__(256) void project_sample_direct_kernel(
    const float* __restrict__ verts,
    const int* __restrict__ faces,
    const float* __restrict__ cam_rot,
    const float* __restrict__ cam_trans,
    const float* __restrict__ Kmat,
    const float* __restrict__ feature,
    const unsigned char* __restrict__ table,
    float* __restrict__ out,
    int n_verts)
{
    int n = blockIdx.x * 4 + (threadIdx.x >> 6);
    int c = threadIdx.x & 63;
    if (n >= n_verts) return;

    float px = verts[n * 3 + 0], py = verts[n * 3 + 1], pz = verts[n * 3 + 2];
    int f = faces[n];
    float xs[NVIEW], ys[NVIEW], mask[NVIEW];
    float vsum = 0.f;
#pragma unroll
    for (int v = 0; v < NVIEW; ++v) {
        project_view(cam_rot, cam_trans, Kmat, v, px, py, pz, xs[v], ys[v]);
        float mm = (f >= 0 && table[(size_t)v * NUM_FACES + f]) ? 1.f : 0.f;
        mask[v] = mm; vsum += mm;
    }
    float wsum = vsum;
    if (vsum == 0.f) {
#pragma unroll
        for (int v = 0; v < NVIEW; ++v) mask[v] = 1.f;
        wsum = (float)NVIEW;
    }
    float acc = 0.f;
#pragma unroll
    for (int v = 0; v < NVIEW; ++v) {
        if (mask[v] == 0.f) continue;
        float x = xs[v], y = ys[v];
        float x0f = floorf(x), y0f = floorf(y);
        float wx1 = x - x0f, wx0 = 1.f - wx1;
        float wy1 = y - y0f, wy0 = 1.f - wy1;
        int x0 = (int)x0f, y0 = (int)y0f;
        int x1 = x0 + 1, y1 = y0 + 1;
        bool vx0 = (x0 >= 0) && (x0 <= IMGS - 1), vx1 = (x1 >= 0) && (x1 <= IMGS - 1);
        bool vy0 = (y0 >= 0) && (y0 <= IMGS - 1), vy1 = (y1 >= 0) && (y1 <= IMGS - 1);
        int cx0 = min(max(x0, 0), IMGS - 1), cx1 = min(max(x1, 0), IMGS - 1);
        int cy0 = min(max(y0, 0), IMGS - 1), cy1 = min(max(y1, 0), IMGS - 1);
        const float* fc = feature + ((size_t)v * NCHAN + c) * (size_t)(IMGS * IMGS);
        acc += fc[cy0 * IMGS + cx0] * (wx0 * wy0 * (float)(vx0 && vy0))
             + fc[cy0 * IMGS + cx1] * (wx1 * wy0 * (float)(vx1 && vy0))
             + fc[cy1 * IMGS + cx0] * (wx0 * wy1 * (float)(vx0 && vy1))
             + fc[cy1 * IMGS + cx1] * (wx1 * wy1 * (float)(vx1 && vy1));
    }
    out[(size_t)n * NCHAN + c] = acc / wsum;
}

extern "C" void kernel_launch(void* const* d_in, const int* in_sizes, int n_in,
                              void* d_out, int out_size, void* d_ws, size_t ws_size,
                              hipStream_t stream) {
    const float* verts     = (const float*)d_in[0];
    const int*   faces     = (const int*)d_in[1];
    const float* cam_rot   = (const float*)d_in[2];
    const float* cam_trans = (const float*)d_in[3];
    const float* Kmat      = (const float*)d_in[4];
    const float* feature   = (const float*)d_in[6];
    const int4*  p2f4      = (const int4*)d_in[7];
    float* out = (float*)d_out;

    int n_verts = in_sizes[1];

    // ws layout: [table][flags32][xyv][vmask][align][feat_t bf16]
    size_t table_sz  = (size_t)NVIEW * NUM_FACES;          // 1,600,000 (16-aligned)
    size_t flag_off  = table_sz;
    size_t flag_sz   = (size_t)NVIEW * IMGS * XT32;        // 32,768
    size_t xyv_off   = (flag_off + flag_sz + 255) & ~(size_t)255;
    size_t xyv_sz    = (size_t)n_verts * 8 * sizeof(float);
    size_t vm_off    = xyv_off + xyv_sz;
    size_t vm_sz     = (size_t)n_verts;
    size_t feat_off  = (vm_off + vm_sz + 255) & ~(size_t)255;
    size_t feat_sz   = (size_t)NVIEW * IMGS * IMGS * NCHAN * sizeof(unsigned short);

    unsigned char* table  = (unsigned char*)d_ws;
    unsigned char* flags  = (unsigned char*)d_ws + flag_off;
    float*         xyv    = (float*)((char*)d_ws + xyv_off);
    unsigned char* vmask  = (unsigned char*)d_ws + vm_off;
    unsigned short* feat_t = (unsigned short*)((char*)d_ws + feat_off);

    const int pix4 = (NVIEW * IMGS * IMGS) / 4;

    if (ws_size >= feat_off + feat_sz) {
        int n16 = (int)((flag_off + flag_sz) / 16);   // exact
        zero_ws_kernel<<<(n16 + 255) / 256, 256, 0, stream>>>((uint4*)d_ws, n16);
        scatter_vis_kernel<<<(pix4 + 255) / 256, 256, 0, stream>>>(p2f4, table);
        vprep_kernel<<<(n_verts + 255) / 256, 256, 0, stream>>>(
            verts, faces, cam_rot, cam_trans, Kmat, table, xyv, vmask, flags, n_verts);
        transpose_feat_kernel<<<NVIEW * IMGS, 256, 0, stream>>>(
            feature, feat_t, flags);
        int sblocks = (n_verts + 4 * VPW - 1) / (4 * VPW);  // 8 vertices/block
        project_sample_bf16_kernel<<<sblocks, 256, 0, stream>>>(
            xyv, vmask, feat_t, out, n_verts);
    } else {
        int n16 = (int)(table_sz / 16);
        zero_ws_kernel<<<(n16 + 255) / 256, 256, 0, stream>>>((uint4*)d_ws, n16);
        scatter_vis_kernel<<<(pix4 + 255) / 256, 256, 0, stream>>>(p2f4, table);
        int nblocks = (n_verts + 3) / 4;
        project_sample_direct_kernel<<<nblocks, 256, 0, stream>>>(
            verts, faces, cam_rot, cam_trans, Kmat, feature, table, out, n_verts);
    }
}

// Round 24
// 140.744 us; speedup vs baseline: 1.0208x; 1.0208x over previous
//
#include <hip/hip_runtime.h>

#define NUM_FACES 400000
#define NVIEW 4
#define NCHAN 64
#define IMGS 512
#define XT32 (IMGS / 32)   // 16 x-tiles of 32 px (one 128 B f32 cache line)
#define VPW 2              // vertices per wave (R19 optimum; 3 regressed twice)

typedef float f32x4 __attribute__((ext_vector_type(4)));
typedef float f32x2 __attribute__((ext_vector_type(2)));

__device__ __forceinline__ unsigned short f2bf(float f) {
    unsigned int u = __float_as_uint(f);
    return (unsigned short)((u + 0x7FFFu + ((u >> 16) & 1u)) >> 16);  // RNE
}

__device__ __forceinline__ void project_view(
    const float* __restrict__ cam_rot, const float* __restrict__ cam_trans,
    const float* __restrict__ Kmat, int v, float px, float py, float pz,
    float& x, float& y)
{
    const float* R  = cam_rot   + v * 9;
    const float* t  = cam_trans + v * 3;
    const float* Km = Kmat      + v * 9;
    float cx = R[0] * px + R[1] * py + R[2] * pz + t[0];
    float cy = R[3] * px + R[4] * py + R[5] * pz + t[1];
    float cz = R[6] * px + R[7] * py + R[8] * pz + t[2];
    float qx = Km[0] * cx + Km[1] * cy + Km[2] * cz;
    float qy = Km[3] * cx + Km[4] * cy + Km[5] * cz;
    float qz = Km[6] * cx + Km[7] * cy + Km[8] * cz;
    x = qx / qz;
    y = qy / qz;
}

// ---------------------------------------------------------------------------
// K0: zero table+flags.
// ---------------------------------------------------------------------------
__global__ void zero_ws_kernel(uint4* __restrict__ p, int n16) {
    int i = blockIdx.x * blockDim.x + threadIdx.x;
    if (i < n16) p[i] = make_uint4(0u, 0u, 0u, 0u);
}

// ---------------------------------------------------------------------------
// K1: scatter pix_to_face (int4-vectorized) into the visibility byte table.
// ---------------------------------------------------------------------------
__global__ void scatter_vis_kernel(const int4* __restrict__ p2f4,
                                   unsigned char* __restrict__ table) {
    const int pix4 = (NVIEW * IMGS * IMGS) / 4;
    int i = blockIdx.x * blockDim.x + threadIdx.x;
    if (i >= pix4) return;
    int4 f4 = p2f4[i];
    int v = i / ((IMGS * IMGS) / 4);
    unsigned char* tv = table + (size_t)v * NUM_FACES;
    if (f4.x >= 0) tv[f4.x] = 1;
    if (f4.y >= 0) tv[f4.y] = 1;
    if (f4.z >= 0) tv[f4.z] = 1;
    if (f4.w >= 0) tv[f4.w] = 1;
}

// ---------------------------------------------------------------------------
// K2: per-vertex prep. Marks touched 32-px tiles using EXACTLY the sampler's
// load addresses (coverage by construction). Writes xyv[N][8] + vmask[N].
// ---------------------------------------------------------------------------
__global__ void vprep_kernel(const float* __restrict__ verts,
                             const int* __restrict__ faces,
                             const float* __restrict__ cam_rot,
                             const float* __restrict__ cam_trans,
                             const float* __restrict__ Kmat,
                             const unsigned char* __restrict__ table, // [V,NUM_FACES]
                             float* __restrict__ xyv,                 // [N,8]
                             unsigned char* __restrict__ vmask,       // [N]
                             unsigned char* __restrict__ flags,       // [V,S,XT32]
                             int n_verts) {
    int n = blockIdx.x * blockDim.x + threadIdx.x;
    if (n >= n_verts) return;
    float px = verts[n * 3 + 0], py = verts[n * 3 + 1], pz = verts[n * 3 + 2];
    int f = faces[n];
    unsigned int m = 0;
    float xy[8];
#pragma unroll
    for (int v = 0; v < NVIEW; ++v) {
        float x, y;
        project_view(cam_rot, cam_trans, Kmat, v, px, py, pz, x, y);
        xy[v * 2 + 0] = x;
        xy[v * 2 + 1] = y;
        if (f >= 0 && table[(size_t)v * NUM_FACES + f]) m |= (1u << v);
        int ix0 = (int)floorf(x), iy0 = (int)floorf(y);
        int bx  = min(max(ix0, 0), IMGS - 2);        // sampler cols bx, bx+1
        int ry0 = min(max(iy0, 0), IMGS - 1);        // sampler rows
        int ry1 = min(max(iy0 + 1, 0), IMGS - 1);
        int ta = bx >> 5, tb = (bx + 1) >> 5;
        unsigned char* fv = flags + (size_t)v * IMGS * XT32;
        fv[ry0 * XT32 + ta] = 1;
        if (tb != ta) fv[ry0 * XT32 + tb] = 1;
        fv[ry1 * XT32 + ta] = 1;
        if (tb != ta) fv[ry1 * XT32 + tb] = 1;
    }
    if (m == 0) m = 15u;
    vmask[n] = (unsigned char)m;
    f32x4 a, b;
    a.x = xy[0]; a.y = xy[1]; a.z = xy[2]; a.w = xy[3];
    b.x = xy[4]; b.y = xy[5]; b.z = xy[6]; b.w = xy[7];
    f32x4* xp = reinterpret_cast<f32x4*>(xyv + (size_t)n * 8);
    xp[0] = a;
    xp[1] = b;
}

// ---------------------------------------------------------------------------
// K3: transpose touched 32-px tiles [V,C,S,S]f32 -> [V,S,S,C]bf16.
// EXACT R15/R19 version (proven at 141.6; runs at ~80-90% of mixed-BW
// ceiling — R23's pipelined row-walk variant was null).
// ---------------------------------------------------------------------------
__global__ __launch_bounds__(256) void transpose_feat_kernel(
    const float* __restrict__ feature,
    unsigned short* __restrict__ feat_t,
    const unsigned char* __restrict__ flags)
{
    int b = blockIdx.x;
    int xt = b % XT32;
    int y  = (b / XT32) % IMGS;
    int v  = b / (XT32 * IMGS);
    if (!flags[((size_t)v * IMGS + y) * XT32 + xt]) return;

    __shared__ float tile[64 * 33];
    int x0 = xt * 32;
    const size_t SS = (size_t)IMGS * IMGS;
    int tid = threadIdx.x;

    const float* src = feature + (size_t)v * NCHAN * SS + (size_t)y * IMGS + x0;
#pragma unroll
    for (int i = 0; i < 2; ++i) {
        int lin = i * 256 + tid;        // 0..511
        int c  = lin >> 3;              // channel 0..63
        int xq = (lin & 7) * 4;         // x quad 0..28
        f32x4 val = __builtin_nontemporal_load(
            reinterpret_cast<const f32x4*>(src + (size_t)c * SS + xq));
        tile[c * 33 + xq + 0] = val.x;
        tile[c * 33 + xq + 1] = val.y;
        tile[c * 33 + xq + 2] = val.z;
        tile[c * 33 + xq + 3] = val.w;
    }
    __syncthreads();

    unsigned short* dst = feat_t + (((size_t)v * IMGS + y) * IMGS + x0) * NCHAN;
#pragma unroll
    for (int i = 0; i < 2; ++i) {
        int lin = i * 256 + tid;        // 0..511
        int x  = lin >> 4;              // pixel 0..31
        int c0 = (lin & 15) * 4;        // channel quad
        ushort4 w;
        w.x = f2bf(tile[(c0 + 0) * 33 + x]);
        w.y = f2bf(tile[(c0 + 1) * 33 + x]);
        w.z = f2bf(tile[(c0 + 2) * 33 + x]);
        w.w = f2bf(tile[(c0 + 3) * 33 + x]);
        *reinterpret_cast<ushort4*>(dst + (size_t)x * NCHAN + c0) = w;
    }
}

// ---------------------------------------------------------------------------
// K4: sampler, VPW=2 (exact R19 kernel — proven 141.6 optimum).
// ---------------------------------------------------------------------------
__global__ __launch_bounds__(256) void project_sample_bf16_kernel(
    const float* __restrict__ xyv,               // [N,8]
    const unsigned char* __restrict__ vmask,     // [N]
    const unsigned short* __restrict__ feat_t,   // [V,S,S,C] bf16
    float* __restrict__ out,                     // [N,C]
    int n_verts)
{
    int n0 = blockIdx.x * (4 * VPW) + (threadIdx.x >> 6) * VPW;
    int lane  = threadIdx.x & 63;
    int lhalf = lane >> 5;
    int cp    = lane & 31;

    unsigned int m[VPW];
    f32x4 xya[VPW], xyb[VPW];
#pragma unroll
    for (int s = 0; s < VPW; ++s) {
        int n = n0 + s;
        if (n < n_verts) {
            m[s] = vmask[n];
            const f32x4* xp = reinterpret_cast<const f32x4*>(xyv + (size_t)n * 8);
            xya[s] = xp[0];
            xyb[s] = xp[1];
        } else {
            m[s] = 0u;          // invalid slot: no loads, no store
            xya[s] = 0.f;
            xyb[s] = 0.f;
        }
    }

    // Phase 1: weights + gather issue for both vertices, all views.
    unsigned int u0[VPW][NVIEW], u1[VPW][NVIEW];
    float w0[VPW][NVIEW], w1[VPW][NVIEW];
#pragma unroll
    for (int s = 0; s < VPW; ++s) {
        float xs[NVIEW] = {xya[s].x, xya[s].z, xyb[s].x, xyb[s].z};
        float ys[NVIEW] = {xya[s].y, xya[s].w, xyb[s].y, xyb[s].w};
#pragma unroll
        for (int v = 0; v < NVIEW; ++v) {
            u0[s][v] = 0u; u1[s][v] = 0u; w0[s][v] = 0.f; w1[s][v] = 0.f;
            if (m[s] & (1u << v)) {   // wave-uniform
                float x = xs[v], y = ys[v];
                float x0f = floorf(x), y0f = floorf(y);
                float wx1 = x - x0f, wx0 = 1.f - wx1;
                float wy1 = y - y0f, wy0 = 1.f - wy1;
                int ix0 = (int)x0f, iy0 = (int)y0f;
                int ix1 = ix0 + 1, iy1 = iy0 + 1;

                int bx = min(max(ix0, 0), IMGS - 2);
                int k  = bx + lhalf;
                float wxk = (k == ix0 ? wx0 : 0.f) + (k == ix1 ? wx1 : 0.f);

                int ry0 = min(max(iy0, 0), IMGS - 1);
                int ry1 = min(max(iy1, 0), IMGS - 1);
                float wyr0 = (iy0 >= 0 && iy0 <= IMGS - 1) ? wy0 : 0.f;
                float wyr1 = (iy1 >= 0 && iy1 <= IMGS - 1) ? wy1 : 0.f;

                const unsigned int* fv32 = reinterpret_cast<const unsigned int*>(
                    feat_t + (size_t)v * IMGS * IMGS * NCHAN);
                u0[s][v] = fv32[((size_t)ry0 * IMGS + bx) * 32 + lane];
                u1[s][v] = fv32[((size_t)ry1 * IMGS + bx) * 32 + lane];
                w0[s][v] = wxk * wyr0;
                w1[s][v] = wxk * wyr1;
            }
        }
    }

    // Phase 2: branch-free accumulate + store, per vertex.
#pragma unroll
    for (int s = 0; s < VPW; ++s) {
        if (m[s] == 0u) continue;   // wave-uniform (only the tail block)
        float accx = 0.f, accy = 0.f;
#pragma unroll
        for (int v = 0; v < NVIEW; ++v) {
            accx += __uint_as_float(u0[s][v] << 16) * w0[s][v]
                  + __uint_as_float(u1[s][v] << 16) * w1[s][v];
            accy += __uint_as_float(u0[s][v] & 0xFFFF0000u) * w0[s][v]
                  + __uint_as_float(u1[s][v] & 0xFFFF0000u) * w1[s][v];
        }
        accx += __shfl_xor(accx, 32, 64);
        accy += __shfl_xor(accy, 32, 64);
        if (lhalf == 0) {
            float r = 1.f / (float)__popc(m[s]);
            f32x2 o; o.x = accx * r; o.y = accy * r;
            __builtin_nontemporal_store(o,
                reinterpret_cast<f32x2*>(out + (size_t)(n0 + s) * NCHAN) + cp);
        }
    }
}

// ---------------------------------------------------------------------------
// Fallback (small ws): direct f32 gather from [V,C,S,S].
// ---------------------------------------------------------------------------
__global__ __launch_bounds__(256) void project_sample_direct_kernel(
    const float* __restrict__ verts,
    const int* __restrict__ faces,
    const float* __restrict__ cam_rot,
    const float* __restrict__ cam_trans,
    const float* __restrict__ Kmat,
    const float* __restrict__ feature,
    const unsigned char* __restrict__ table,
    float* __restrict__ out,
    int n_verts)
{
    int n = blockIdx.x * 4 + (threadIdx.x >> 6);
    int c = threadIdx.x & 63;
    if (n >= n_verts) return;

    float px = verts[n * 3 + 0], py = verts[n * 3 + 1], pz = verts[n * 3 + 2];
    int f = faces[n];
    float xs[NVIEW], ys[NVIEW], mask[NVIEW];
    float vsum = 0.f;
#pragma unroll
    for (int v = 0; v < NVIEW; ++v) {
        project_view(cam_rot, cam_trans, Kmat, v, px, py, pz, xs[v], ys[v]);
        float mm = (f >= 0 && table[(size_t)v * NUM_FACES + f]) ? 1.f : 0.f;
        mask[v] = mm; vsum += mm;
    }
    float wsum = vsum;
    if (vsum == 0.f) {
#pragma unroll
        for (int v = 0; v < NVIEW; ++v) mask[v] = 1.f;
        wsum = (float)NVIEW;
    }
    float acc = 0.f;
#pragma unroll
    for (int v = 0; v < NVIEW; ++v) {
        if (mask[v] == 0.f) continue;
        float x = xs[v], y = ys[v];
        float x0f = floorf(x), y0f = floorf(y);
        float wx1 = x - x0f, wx0 = 1.f - wx1;
        float wy1 = y - y0f, wy0 = 1.f - wy1;
        int x0 = (int)x0f, y0 = (int)y0f;
        int x1 = x0 + 1, y1 = y0 + 1;
        bool vx0 = (x0 >= 0) && (x0 <= IMGS - 1), vx1 = (x1 >= 0) && (x1 <= IMGS - 1);
        bool vy0 = (y0 >= 0) && (y0 <= IMGS - 1), vy1 = (y1 >= 0) && (y1 <= IMGS - 1);
        int cx0 = min(max(x0, 0), IMGS - 1), cx1 = min(max(x1, 0), IMGS - 1);
        int cy0 = min(max(y0, 0), IMGS - 1), cy1 = min(max(y1, 0), IMGS - 1);
        const float* fc = feature + ((size_t)v * NCHAN + c) * (size_t)(IMGS * IMGS);
        acc += fc[cy0 * IMGS + cx0] * (wx0 * wy0 * (float)(vx0 && vy0))
             + fc[cy0 * IMGS + cx1] * (wx1 * wy0 * (float)(vx1 && vy0))
             + fc[cy1 * IMGS + cx0] * (wx0 * wy1 * (float)(vx0 && vy1))
             + fc[cy1 * IMGS + cx1] * (wx1 * wy1 * (float)(vx1 && vy1));
    }
    out[(size_t)n * NCHAN + c] = acc / wsum;
}

extern "C" void kernel_launch(void* const* d_in, const int* in_sizes, int n_in,
                              void* d_out, int out_size, void* d_ws, size_t ws_size,
                              hipStream_t stream) {
    const float* verts     = (const float*)d_in[0];
    const int*   faces     = (const int*)d_in[1];
    const float* cam_rot   = (const float*)d_in[2];
    const float* cam_trans = (const float*)d_in[3];
    const float* Kmat      = (const float*)d_in[4];
    const float* feature   = (const float*)d_in[6];
    const int4*  p2f4      = (const int4*)d_in[7];
    float* out = (float*)d_out;

    int n_verts = in_sizes[1];

    // ws layout: [table][flags32][xyv][vmask][align][feat_t bf16]
    size_t table_sz  = (size_t)NVIEW * NUM_FACES;          // 1,600,000
    size_t flag_off  = table_sz;
    size_t flag_sz   = (size_t)NVIEW * IMGS * XT32;        // 32,768
    size_t xyv_off   = (flag_off + flag_sz + 255) & ~(size_t)255;
    size_t xyv_sz    = (size_t)n_verts * 8 * sizeof(float);
    size_t vm_off    = xyv_off + xyv_sz;
    size_t vm_sz     = (size_t)n_verts;
    size_t feat_off  = (vm_off + vm_sz + 255) & ~(size_t)255;
    size_t feat_sz   = (size_t)NVIEW * IMGS * IMGS * NCHAN * sizeof(unsigned short);

    unsigned char* table  = (unsigned char*)d_ws;
    unsigned char* flags  = (unsigned char*)d_ws + flag_off;
    float*         xyv    = (float*)((char*)d_ws + xyv_off);
    unsigned char* vmask  = (unsigned char*)d_ws + vm_off;
    unsigned short* feat_t = (unsigned short*)((char*)d_ws + feat_off);

    const int pix4 = (NVIEW * IMGS * IMGS) / 4;

    if (ws_size >= feat_off + feat_sz) {
        int n16 = (int)((flag_off + flag_sz) / 16);   // exact
        zero_ws_kernel<<<(n16 + 255) / 256, 256, 0, stream>>>((uint4*)d_ws, n16);
        scatter_vis_kernel<<<(pix4 + 255) / 256, 256, 0, stream>>>(p2f4, table);
        vprep_kernel<<<(n_verts + 255) / 256, 256, 0, stream>>>(
            verts, faces, cam_rot, cam_trans, Kmat, table, xyv, vmask, flags, n_verts);
        transpose_feat_kernel<<<NVIEW * IMGS * XT32, 256, 0, stream>>>(
            feature, feat_t, flags);
        int sblocks = (n_verts + 4 * VPW - 1) / (4 * VPW);  // 8 vertices/block
        project_sample_bf16_kernel<<<sblocks, 256, 0, stream>>>(
            xyv, vmask, feat_t, out, n_verts);
    } else {
        int n16 = (int)(table_sz / 16);
        zero_ws_kernel<<<(n16 + 255) / 256, 256, 0, stream>>>((uint4*)d_ws, n16);
        scatter_vis_kernel<<<(pix4 + 255) / 256, 256, 0, stream>>>(p2f4, table);
        int nblocks = (n_verts + 3) / 4;
        project_sample_direct_kernel<<<nblocks, 256, 0, stream>>>(
            verts, faces, cam_rot, cam_trans, Kmat, feature, table, out, n_verts);
    }
}